// Round 10
// baseline (470.677 us; speedup 1.0000x reference)
//
#include <hip/hip_runtime.h>
#include <math.h>

// ---------------------------------------------------------------------------
// GraphSAGE (max aggr) x2 + LN + ReLU + MLP head + sigmoid.
// CSR build via 2-level LDS-staged counting sort (no N-wide global atomics).
// Layer-1 gather uses XCD FEATURE-SLICING: h0 stored as 8 planes of 32 B/row;
// slice = blockIdx&7 (round-robin XCD proxy) so each plane's lines are pulled
// through ~one XCD's L2. Round-7/9 analysis: row-major gather forces every
// XCD to fill ~all of h0 (180 MB structural; measured 3.6 TB/s fabric floor,
// instruction shape irrelevant). Planes cut payload fill to ~26 MB at the
// cost of per-XCD csr re-reads (~51 MB streamed).
// Layer-0 gather: round-7 monotone-u16 pk_max form (round-9 wide variant
// regressed; reverted). MFMA GEMM layers read pre-packed bf16 B-fragments
// from global; k_lin1 reads h0 root-half from planes; h1 in-place over agg1.
// Workspace ~58.9 MB, same aliasing as the 322-us round-7 config.
// ---------------------------------------------------------------------------

static inline int ceil_div(int a, int b) { return (a + b - 1) / b; }

typedef unsigned int uint;
typedef __attribute__((ext_vector_type(8))) short short8;
typedef __attribute__((ext_vector_type(4))) float f32x4;

#define NBSHIFT 8     // bucket = 256 dst nodes
#define ACHUNK 4096   // edges per pass-A block
#define BCAP 6144     // LDS csr-window capacity per bucket

// RTNE float -> bf16
__device__ __forceinline__ unsigned short f2bf(float f) {
  uint u = __float_as_uint(f);
  u += 0x7fffu + ((u >> 16) & 1u);
  return (unsigned short)(u >> 16);
}
__device__ __forceinline__ float bfval(unsigned short b) {
  return __uint_as_float((uint)b << 16);
}
__device__ __forceinline__ uint pack2(float lo, float hi) {
  return (uint)f2bf(lo) | ((uint)f2bf(hi) << 16);
}
// packed unsigned 16-bit max (bf16>=0 compares correctly as u16)
__device__ __forceinline__ uint pkmaxu16(uint a, uint b) {
  uint r;
  asm("v_pk_max_u16 %0, %1, %2" : "=v"(r) : "v"(a), "v"(b));
  return r;
}
__device__ __forceinline__ uint4 pkmax4(uint4 a, uint4 b) {
  uint4 r;
  r.x = pkmaxu16(a.x, b.x);
  r.y = pkmaxu16(a.y, b.y);
  r.z = pkmaxu16(a.z, b.z);
  r.w = pkmaxu16(a.w, b.w);
  return r;
}

// ---- bucket histogram (LDS-aggregated) ------------------------------------

__global__ __launch_bounds__(256) void k_bhist(const int* __restrict__ dst,
                                               int* __restrict__ gbtot, int E) {
  __shared__ int bcnt[512];
  int tid = threadIdx.x;
  for (int i = tid; i < 512; i += 256) bcnt[i] = 0;
  __syncthreads();
  int c0 = blockIdx.x * ACHUNK;
  int cend = min(c0 + ACHUNK, E);
  for (int e = c0 + tid; e < cend; e += 256)
    atomicAdd(&bcnt[dst[e] >> NBSHIFT], 1);
  __syncthreads();
  for (int i = tid; i < 512; i += 256) {
    int c = bcnt[i];
    if (c) atomicAdd(&gbtot[i], c);
  }
}

// ---- bucket scan ----------------------------------------------------------

__global__ __launch_bounds__(512) void k_bscan(const int* __restrict__ gbtot,
                                               int* __restrict__ gbase,
                                               int* __restrict__ gbcur) {
  __shared__ int tmp[512];
  int v = gbtot[threadIdx.x];
  tmp[threadIdx.x] = v;
  __syncthreads();
  for (int off = 1; off < 512; off <<= 1) {
    int t = (threadIdx.x >= off) ? tmp[threadIdx.x - off] : 0;
    __syncthreads();
    tmp[threadIdx.x] += t;
    __syncthreads();
  }
  int ex = tmp[threadIdx.x] - v;
  gbase[threadIdx.x] = ex;
  gbcur[threadIdx.x] = ex;
}

// ---- Pass A: counting-sort edges into bucket-grouped bed[] ----------------

__global__ __launch_bounds__(256) void k_passA(const int* __restrict__ src,
                                               const int* __restrict__ dst,
                                               int* __restrict__ gbcur,
                                               int2* __restrict__ bed, int E) {
  __shared__ int bcnt[512];
  __shared__ int lbase[512];
  __shared__ int bbase[512];
  __shared__ int lcur[512];
  __shared__ int2 sbed[ACHUNK];
  int tid = threadIdx.x;
  int c0 = blockIdx.x * ACHUNK;
  int cend = min(c0 + ACHUNK, E);
  int total = cend - c0;
  for (int i = tid; i < 512; i += 256) bcnt[i] = 0;
  __syncthreads();
  for (int e = c0 + tid; e < cend; e += 256)
    atomicAdd(&bcnt[dst[e] >> NBSHIFT], 1);
  __syncthreads();
  for (int i = tid; i < 512; i += 256) lbase[i] = bcnt[i];
  __syncthreads();
  for (int off = 1; off < 512; off <<= 1) {
    int i0 = tid, i1 = tid + 256;
    int v0 = (i0 >= off) ? lbase[i0 - off] : 0;
    int v1 = (i1 >= off) ? lbase[i1 - off] : 0;
    __syncthreads();
    lbase[i0] += v0;
    lbase[i1] += v1;
    __syncthreads();
  }
  for (int i = tid; i < 512; i += 256) {
    int c = bcnt[i];
    bbase[i] = (c > 0) ? atomicAdd(&gbcur[i], c) : 0;
    lcur[i] = 0;
  }
  __syncthreads();
  for (int e = c0 + tid; e < cend; e += 256) {
    int s = src[e], d = dst[e];
    int b = d >> NBSHIFT;
    int lp = atomicAdd(&lcur[b], 1);
    sbed[lbase[b] - bcnt[b] + lp] = make_int2(s, d);
  }
  __syncthreads();
  for (int j = tid; j < total; j += 256) {
    int2 pr = sbed[j];
    int b = pr.y >> NBSHIFT;
    bed[bbase[b] + (j - (lbase[b] - bcnt[b]))] = pr;
  }
}

// ---- Pass B: one block per bucket; degrees/row-starts in LDS --------------

__global__ __launch_bounds__(256) void k_passB(const int2* __restrict__ bed,
                                               const int* __restrict__ gbase,
                                               int* __restrict__ counts,
                                               int* __restrict__ rowst,
                                               int* __restrict__ csr, int N, int E) {
  __shared__ int cnt[256];
  __shared__ int scn[256];
  __shared__ int lcur[256];
  __shared__ int scsr[BCAP];
  int b = blockIdx.x, tid = threadIdx.x;
  int n0 = b << NBSHIFT;
  int n1 = min(n0 + 256, N);
  int e0 = gbase[b];
  int e1 = (b + 1 < 512) ? gbase[b + 1] : E;
  if (b + 1 == gridDim.x) e1 = E;
  int sz = e1 - e0;
  cnt[tid] = 0;
  __syncthreads();
  for (int e = e0 + tid; e < e1; e += 256)
    atomicAdd(&cnt[bed[e].y - n0], 1);
  __syncthreads();
  scn[tid] = cnt[tid];
  __syncthreads();
  for (int off = 1; off < 256; off <<= 1) {
    int t = (tid >= off) ? scn[tid - off] : 0;
    __syncthreads();
    scn[tid] += t;
    __syncthreads();
  }
  int ex = scn[tid] - cnt[tid];
  if (n0 + tid < n1) {
    counts[n0 + tid] = cnt[tid];
    rowst[n0 + tid] = e0 + ex;
  }
  lcur[tid] = ex;
  __syncthreads();
  if (sz <= BCAP) {
    for (int e = e0 + tid; e < e1; e += 256) {
      int2 pr = bed[e];
      int p = atomicAdd(&lcur[pr.y - n0], 1);
      scsr[p] = pr.x;
    }
    __syncthreads();
    for (int j = tid; j < sz; j += 256) csr[e0 + j] = scsr[j];
  } else {  // statistical overflow fallback (correct, slower)
    for (int e = e0 + tid; e < e1; e += 256) {
      int2 pr = bed[e];
      int p = atomicAdd(&lcur[pr.y - n0], 1);
      csr[e0 + p] = pr.x;
    }
  }
}

// ---- Prep: x fp32 [N][64] -> xb (packed bf16) + xm (monotone u16) ---------

__global__ __launch_bounds__(256) void k_prep(const float* __restrict__ x,
                                              uint* __restrict__ xb,
                                              uint* __restrict__ xm, int total) {
  int i = blockIdx.x * 256 + threadIdx.x;
  if (i < total) {
    float2 v = ((const float2*)x)[i];
    uint p = pack2(v.x, v.y);
    xb[i] = p;
    uint lo = p & 0xFFFFu, hi = p >> 16;
    lo = (lo & 0x8000u) ? (~lo & 0xFFFFu) : (lo | 0x8000u);
    hi = (hi & 0x8000u) ? (~hi & 0xFFFFu) : (hi | 0x8000u);
    xm[i] = lo | (hi << 16);
  }
}

// ---- Weight prep: pack all GEMM B-operands as bf16 fragments --------------

__global__ __launch_bounds__(256) void k_wprep(
    const float* __restrict__ Wl0, const float* __restrict__ Wr0,
    const float* __restrict__ Wl1, const float* __restrict__ Wr1,
    const float* __restrict__ W1m,
    uint4* __restrict__ wB0, uint4* __restrict__ wB1, uint4* __restrict__ wBm) {
  int i = blockIdx.x * 256 + threadIdx.x;
  if (i < 4096) {
    int lane = i & 63, jt = (i >> 6) & 7, ks = i >> 9;
    int m = lane & 15, q = lane >> 4;
    int j = jt * 16 + m;
    int half = ks >> 2;             // 0 = hi, 1 = lo
    int kk = (ks & 3) * 32 + q * 8; // 0..120
    const float* srcr = (kk < 64) ? (Wl0 + (size_t)j * 64 + kk)
                                  : (Wr0 + (size_t)j * 64 + (kk - 64));
    float4 w0 = ((const float4*)srcr)[0];
    float4 w1 = ((const float4*)srcr)[1];
    float v[8] = {w0.x, w0.y, w0.z, w0.w, w1.x, w1.y, w1.z, w1.w};
    unsigned short b16[8];
#pragma unroll
    for (int t = 0; t < 8; t++) {
      unsigned short hi = f2bf(v[t]);
      b16[t] = half ? f2bf(v[t] - bfval(hi)) : hi;
    }
    uint4 p;
    p.x = (uint)b16[0] | ((uint)b16[1] << 16);
    p.y = (uint)b16[2] | ((uint)b16[3] << 16);
    p.z = (uint)b16[4] | ((uint)b16[5] << 16);
    p.w = (uint)b16[6] | ((uint)b16[7] << 16);
    wB0[i] = p;
  } else if (i < 8192) {
    int e = i - 4096;
    int lane = e & 63, jt = (e >> 6) & 7, ks = e >> 9;
    int m = lane & 15, q = lane >> 4;
    int j = jt * 16 + m;
    int k0 = ks * 32 + q * 8;  // 0..248
    const float* srcr = (k0 < 128) ? (Wl1 + (size_t)j * 128 + k0)
                                   : (Wr1 + (size_t)j * 128 + (k0 - 128));
    float4 w0 = ((const float4*)srcr)[0];
    float4 w1 = ((const float4*)srcr)[1];
    uint4 p;
    p.x = pack2(w0.x, w0.y);
    p.y = pack2(w0.z, w0.w);
    p.z = pack2(w1.x, w1.y);
    p.w = pack2(w1.z, w1.w);
    wB1[e] = p;
  } else if (i < 9216) {
    int e = i - 8192;
    int lane = e & 63, jt = (e >> 6) & 3, ks = e >> 8;
    int m = lane & 15, q = lane >> 4;
    int j = jt * 16 + m;          // 0..63
    int k0 = ks * 32 + q * 8;     // 0..120
    const float* srcr = W1m + (size_t)j * 128 + k0;
    float4 w0 = ((const float4*)srcr)[0];
    float4 w1 = ((const float4*)srcr)[1];
    uint4 p;
    p.x = pack2(w0.x, w0.y);
    p.y = pack2(w0.z, w0.w);
    p.z = pack2(w1.x, w1.y);
    p.w = pack2(w1.z, w1.w);
    wBm[e] = p;
  }
}

// ---- Aggregation layer 0 (round-7 form): monotone-u16 pk_max, 2 nodes/wave

__global__ __launch_bounds__(256) void k_agg0b(const uint* __restrict__ xm,
                                               const int* __restrict__ rowst,
                                               const int* __restrict__ deg,
                                               const int* __restrict__ csr,
                                               uint* __restrict__ agg, int N) {
  int lane = threadIdx.x & 63;
  int sub = lane >> 5, ll = lane & 31;
  int h = sub << 5;
  int w = (blockIdx.x * 256 + threadIdx.x) >> 6;
  int nw = (gridDim.x * 256) >> 6;
  for (int n0 = w * 2; n0 < N; n0 += nw * 2) {
    int n = n0 + sub;
    bool valid = (n < N);
    int myn = valid ? n : (N - 1);
    int rs = rowst[myn], d = deg[myn];
    int dmax = max(d, __shfl_xor(d, 32));
    int fb = (d > 0) ? csr[rs] : 0;
    uint m = 0;
    for (int base = 0; base < dmax; base += 32) {
      int cnt = min(max(d - base, 0), 32);
      int cmax = min(dmax - base, 32);
      int idx = (ll < cnt) ? csr[rs + base + ll] : fb;
      for (int j = 0; j < cmax; j += 8) {
        uint u0 = xm[(size_t)__shfl(idx, h + j + 0) * 32 + ll];
        uint u1 = xm[(size_t)__shfl(idx, h + j + 1) * 32 + ll];
        uint u2 = xm[(size_t)__shfl(idx, h + j + 2) * 32 + ll];
        uint u3 = xm[(size_t)__shfl(idx, h + j + 3) * 32 + ll];
        uint u4 = xm[(size_t)__shfl(idx, h + j + 4) * 32 + ll];
        uint u5 = xm[(size_t)__shfl(idx, h + j + 5) * 32 + ll];
        uint u6 = xm[(size_t)__shfl(idx, h + j + 6) * 32 + ll];
        uint u7 = xm[(size_t)__shfl(idx, h + j + 7) * 32 + ll];
        m = pkmaxu16(m, pkmaxu16(pkmaxu16(pkmaxu16(u0, u1), pkmaxu16(u2, u3)),
                                 pkmaxu16(pkmaxu16(u4, u5), pkmaxu16(u6, u7))));
      }
    }
    if (valid) {
      uint lo = m & 0xFFFFu, hi = m >> 16;
      lo = (lo & 0x8000u) ? (lo ^ 0x8000u) : (~lo & 0xFFFFu);
      hi = (hi & 0x8000u) ? (hi ^ 0x8000u) : (~hi & 0xFFFFu);
      agg[(size_t)n * 32 + ll] = (d > 0) ? (lo | (hi << 16)) : 0u;
    }
  }
}

// ---- Aggregation layer 1, XCD-SLICED: plane s only, 32 edges/instr --------
// h0p = 8 planes; plane p holds rows of 2 uint4 (32 B = features p*16..p*16+15).
// slice = blockIdx&7 (round-robin XCD proxy). Output row-major (in-place-safe
// for k_lin1). h0 >= 0 so pk_max_u16 with neutral 0.

__global__ __launch_bounds__(256) void k_agg1s(const uint4* __restrict__ h0p,
                                               const int* __restrict__ rowst,
                                               const int* __restrict__ deg,
                                               const int* __restrict__ csr,
                                               uint4* __restrict__ agg, int N) {
  int lane = threadIdx.x & 63;
  int es = lane >> 1, fh = lane & 1;
  int s = blockIdx.x & 7;
  const uint4* plane = h0p + (size_t)s * N * 2;
  int wid = (((blockIdx.x >> 3) * 256 + threadIdx.x)) >> 6;
  int nw = ((gridDim.x >> 3) * 256) >> 6;
  for (int n = wid; n < N; n += nw) {
    int rs = rowst[n], d = deg[n];
    uint4 m = {0u, 0u, 0u, 0u};
    if (d > 0) {
      int fb = csr[rs];  // duplicate pad: max is idempotent
      for (int base = 0; base < d; base += 64) {
        int cnt = min(d - base, 64);
        int idx = (lane < cnt) ? csr[rs + base + lane] : fb;
        m = pkmax4(m, plane[(size_t)__shfl(idx, es) * 2 + fh]);
        if (cnt > 32)
          m = pkmax4(m, plane[(size_t)__shfl(idx, 32 + es) * 2 + fh]);
      }
    }
    // fold the 32 edge subgroups (lanes differing in bits 1..5)
#pragma unroll
    for (int off = 2; off < 64; off <<= 1) {
      m.x = pkmaxu16(m.x, __shfl_xor(m.x, off));
      m.y = pkmaxu16(m.y, __shfl_xor(m.y, off));
      m.z = pkmaxu16(m.z, __shfl_xor(m.z, off));
      m.w = pkmaxu16(m.w, __shfl_xor(m.w, off));
    }
    if (lane < 2) agg[(size_t)n * 16 + s * 2 + fh] = m;
  }
}

// ---- Layer 0: h0(planes) = LNrelu([agg0|x] @ [Wl0|Wr0]^T + bl0) -----------
// Output plane jt = features jt*16..jt*16+15, row = 16 shorts.

__global__ __launch_bounds__(256) void k_lin0(
    const uint* __restrict__ agg,  // N x 32 uints (bf16 [N][64])
    const uint* __restrict__ xb,   // N x 32 uints
    const uint4* __restrict__ wB,  // 4096 frag entries
    const float* __restrict__ bl, const float* __restrict__ g,
    const float* __restrict__ be, unsigned short* __restrict__ hout, int N) {
  int lane = threadIdx.x & 63, m = lane & 15, q = lane >> 4;
  int w = (blockIdx.x * 256 + threadIdx.x) >> 6;
  int nw = (gridDim.x * 256) >> 6;
  int pairs = (N + 31) / 32;
  float blv[8], gv[8], bev[8];
#pragma unroll
  for (int jt = 0; jt < 8; jt++) {
    blv[jt] = bl[jt * 16 + m];
    gv[jt] = g[jt * 16 + m];
    bev[jt] = be[jt * 16 + m];
  }
  for (int p = w; p < pairs; p += nw) {
    int b0 = p * 32;
    short8 a[2][4];
#pragma unroll
    for (int t = 0; t < 2; t++) {
      int row = b0 + t * 16 + m;
      const uint* r0 = agg + (size_t)row * 32;
      const uint* r1 = xb + (size_t)row * 32;
#pragma unroll
      for (int ks = 0; ks < 4; ks++) {
        const uint* base = (ks < 2) ? r0 : r1;
        a[t][ks] = __builtin_bit_cast(short8, *(const uint4*)(base + (ks & 1) * 16 + q * 4));
      }
    }
    f32x4 acc[2][8];
#pragma unroll
    for (int t = 0; t < 2; t++)
#pragma unroll
      for (int jt = 0; jt < 8; jt++) acc[t][jt] = {0.f, 0.f, 0.f, 0.f};
#pragma unroll
    for (int ks = 0; ks < 8; ks++) {
#pragma unroll
      for (int jt = 0; jt < 8; jt++) {
        short8 b = __builtin_bit_cast(short8, wB[(ks * 8 + jt) * 64 + lane]);
        acc[0][jt] = __builtin_amdgcn_mfma_f32_16x16x32_bf16(a[0][ks & 3], b, acc[0][jt], 0, 0, 0);
        acc[1][jt] = __builtin_amdgcn_mfma_f32_16x16x32_bf16(a[1][ks & 3], b, acc[1][jt], 0, 0, 0);
      }
    }
#pragma unroll
    for (int t = 0; t < 2; t++) {
      float s1[4] = {0.f, 0.f, 0.f, 0.f}, s2[4] = {0.f, 0.f, 0.f, 0.f};
#pragma unroll
      for (int jt = 0; jt < 8; jt++) {
        float bb = blv[jt];
#pragma unroll
        for (int r = 0; r < 4; r++) {
          float v = acc[t][jt][r] + bb;
          s1[r] += v;
          s2[r] += v * v;
        }
      }
#pragma unroll
      for (int off = 1; off < 16; off <<= 1) {
#pragma unroll
        for (int r = 0; r < 4; r++) {
          s1[r] += __shfl_xor(s1[r], off);
          s2[r] += __shfl_xor(s2[r], off);
        }
      }
      float mu[4], rstd[4];
#pragma unroll
      for (int r = 0; r < 4; r++) {
        mu[r] = s1[r] * (1.0f / 128.0f);
        float var = s2[r] * (1.0f / 128.0f) - mu[r] * mu[r];
        rstd[r] = rsqrtf(var + 1e-5f);
      }
      int nodeb = b0 + t * 16 + q * 4;
#pragma unroll
      for (int jt = 0; jt < 8; jt++) {
        float bb = blv[jt];
#pragma unroll
        for (int r = 0; r < 4; r++) {
          int node = nodeb + r;
          if (node < N) {
            float v = acc[t][jt][r] + bb;
            float o = fmaxf((v - mu[r]) * rstd[r] * gv[jt] + bev[jt], 0.0f);
            hout[((size_t)jt * N + node) * 16 + m] = f2bf(o);  // plane layout
          }
        }
      }
    }
  }
}

// ---- Layer 1: h1 = LNrelu([agg1|h0] @ [Wl1|Wr1]^T + bl1), in-place --------
// agg half from row-major agg1; root half from h0 planes.

__global__ __launch_bounds__(256) void k_lin1(
    uint* agg,                     // N x 64 uints; becomes h1 (bf16 [N][128])
    const uint* __restrict__ h0u,  // 8 planes of N x 8 uints
    const uint4* __restrict__ wB,  // 4096 frag entries
    const float* __restrict__ bl, const float* __restrict__ g,
    const float* __restrict__ be, int N) {
  int lane = threadIdx.x & 63, m = lane & 15, q = lane >> 4;
  int w = (blockIdx.x * 256 + threadIdx.x) >> 6;
  int nw = (gridDim.x * 256) >> 6;
  int pairs = (N + 31) / 32;
  float blv[8], gv[8], bev[8];
#pragma unroll
  for (int jt = 0; jt < 8; jt++) {
    blv[jt] = bl[jt * 16 + m];
    gv[jt] = g[jt * 16 + m];
    bev[jt] = be[jt * 16 + m];
  }
  unsigned short* hout = (unsigned short*)agg;
  for (int p = w; p < pairs; p += nw) {
    int b0 = p * 32;
    short8 a[2][8];
#pragma unroll
    for (int t = 0; t < 2; t++) {
      int row = b0 + t * 16 + m;
      const uint* r0 = agg + (size_t)row * 64;
#pragma unroll
      for (int ks = 0; ks < 4; ks++)
        a[t][ks] = __builtin_bit_cast(short8, *(const uint4*)(r0 + ks * 16 + q * 4));
#pragma unroll
      for (int ks = 0; ks < 4; ks++) {
        int pl = 2 * ks + (q >> 1);
        a[t][ks + 4] = __builtin_bit_cast(
            short8, *(const uint4*)(h0u + ((size_t)pl * N + row) * 8 + (q & 1) * 4));
      }
    }
    f32x4 acc[2][8];
#pragma unroll
    for (int t = 0; t < 2; t++)
#pragma unroll
      for (int jt = 0; jt < 8; jt++) acc[t][jt] = {0.f, 0.f, 0.f, 0.f};
#pragma unroll
    for (int ks = 0; ks < 8; ks++) {
#pragma unroll
      for (int jt = 0; jt < 8; jt++) {
        short8 b = __builtin_bit_cast(short8, wB[(ks * 8 + jt) * 64 + lane]);
        acc[0][jt] = __builtin_amdgcn_mfma_f32_16x16x32_bf16(a[0][ks], b, acc[0][jt], 0, 0, 0);
        acc[1][jt] = __builtin_amdgcn_mfma_f32_16x16x32_bf16(a[1][ks], b, acc[1][jt], 0, 0, 0);
      }
    }
#pragma unroll
    for (int t = 0; t < 2; t++) {
      float s1[4] = {0.f, 0.f, 0.f, 0.f}, s2[4] = {0.f, 0.f, 0.f, 0.f};
#pragma unroll
      for (int jt = 0; jt < 8; jt++) {
        float bb = blv[jt];
#pragma unroll
        for (int r = 0; r < 4; r++) {
          float v = acc[t][jt][r] + bb;
          s1[r] += v;
          s2[r] += v * v;
        }
      }
#pragma unroll
      for (int off = 1; off < 16; off <<= 1) {
#pragma unroll
        for (int r = 0; r < 4; r++) {
          s1[r] += __shfl_xor(s1[r], off);
          s2[r] += __shfl_xor(s2[r], off);
        }
      }
      float mu[4], rstd[4];
#pragma unroll
      for (int r = 0; r < 4; r++) {
        mu[r] = s1[r] * (1.0f / 128.0f);
        float var = s2[r] * (1.0f / 128.0f) - mu[r] * mu[r];
        rstd[r] = rsqrtf(var + 1e-5f);
      }
      int nodeb = b0 + t * 16 + q * 4;
#pragma unroll
      for (int jt = 0; jt < 8; jt++) {
        float bb = blv[jt];
#pragma unroll
        for (int r = 0; r < 4; r++) {
          int node = nodeb + r;
          if (node < N) {
            float v = acc[t][jt][r] + bb;
            float o = fmaxf((v - mu[r]) * rstd[r] * gv[jt] + bev[jt], 0.0f);
            hout[(size_t)node * 128 + jt * 16 + m] = f2bf(o);
          }
        }
      }
    }
  }
}

// ---- MLP head: out = sigmoid(relu(h1@W1.T+b1) @ W2.T + b2) ----------------

__global__ __launch_bounds__(256) void k_mlp(const uint* __restrict__ h1,
                                             const uint4* __restrict__ wB,
                                             const float* __restrict__ b1,
                                             const float* __restrict__ W2,
                                             const float* __restrict__ b2,
                                             float* __restrict__ out, int N) {
  int lane = threadIdx.x & 63, m = lane & 15, q = lane >> 4;
  int w = (blockIdx.x * 256 + threadIdx.x) >> 6;
  int nw = (gridDim.x * 256) >> 6;
  int tiles = (N + 15) / 16;
  float b1v[4], w2v[4];
#pragma unroll
  for (int jt = 0; jt < 4; jt++) {
    b1v[jt] = b1[jt * 16 + m];
    w2v[jt] = W2[jt * 16 + m];
  }
  float b2v = b2[0];
  for (int tl = w; tl < tiles; tl += nw) {
    int b0 = tl * 16;
    int row = min(b0 + m, N - 1);
    const uint* r0 = h1 + (size_t)row * 64;
    short8 a[4];
#pragma unroll
    for (int ks = 0; ks < 4; ks++)
      a[ks] = __builtin_bit_cast(short8, *(const uint4*)(r0 + ks * 16 + q * 4));
    f32x4 acc[4];
#pragma unroll
    for (int jt = 0; jt < 4; jt++) acc[jt] = {0.f, 0.f, 0.f, 0.f};
#pragma unroll
    for (int ks = 0; ks < 4; ks++) {
#pragma unroll
      for (int jt = 0; jt < 4; jt++) {
        short8 b = __builtin_bit_cast(short8, wB[(ks * 4 + jt) * 64 + lane]);
        acc[jt] = __builtin_amdgcn_mfma_f32_16x16x32_bf16(a[ks], b, acc[jt], 0, 0, 0);
      }
    }
    float part[4] = {0.f, 0.f, 0.f, 0.f};
#pragma unroll
    for (int jt = 0; jt < 4; jt++) {
#pragma unroll
      for (int r = 0; r < 4; r++)
        part[r] += fmaxf(acc[jt][r] + b1v[jt], 0.0f) * w2v[jt];
    }
#pragma unroll
    for (int off = 1; off < 16; off <<= 1) {
#pragma unroll
      for (int r = 0; r < 4; r++) part[r] += __shfl_xor(part[r], off);
    }
    if (m == 0) {
#pragma unroll
      for (int r = 0; r < 4; r++) {
        int node = b0 + q * 4 + r;
        if (node < N) out[node] = 1.0f / (1.0f + expf(-(part[r] + b2v)));
      }
    }
  }
}

// ---------------------------------------------------------------------------

extern "C" void kernel_launch(void* const* d_in, const int* in_sizes, int n_in,
                              void* d_out, int out_size, void* d_ws, size_t ws_size,
                              hipStream_t stream) {
  const float* x = (const float*)d_in[0];
  const int* ei = (const int*)d_in[1];
  const float* Wl0 = (const float*)d_in[2];
  const float* bl0 = (const float*)d_in[3];
  const float* Wr0 = (const float*)d_in[4];
  const float* g0 = (const float*)d_in[5];
  const float* be0 = (const float*)d_in[6];
  const float* Wl1 = (const float*)d_in[7];
  const float* bl1 = (const float*)d_in[8];
  const float* Wr1 = (const float*)d_in[9];
  const float* g1 = (const float*)d_in[10];
  const float* be1 = (const float*)d_in[11];
  const float* W1 = (const float*)d_in[12];
  const float* b1 = (const float*)d_in[13];
  const float* W2 = (const float*)d_in[14];
  const float* b2 = (const float*)d_in[15];
  float* out = (float*)d_out;

  const int N = in_sizes[0] / 64;
  const int E = in_sizes[1] / 2;
  const int* src = ei;
  const int* dst = ei + E;
  const int nb = ceil_div(N, 1 << NBSHIFT);

  // Workspace (~58.9 MB peak):
  //   misc + csr (6.4 MB) + regionX (25.6 MB) + h0buf (25.6 MB) + wB (144 KB)
  // h0buf timeline: [bed 12.8 | xm 12.8] -> h0 planes (k_lin0 onward).
  // regionX timeline: [xb | agg0b] -> agg1 (row-major) -> h1 (in-place).
  char* ws = (char*)d_ws;
  size_t off = 0;
  auto alloc = [&](size_t bytes) -> void* {
    void* p = ws + off;
    off = (off + bytes + 255) & ~(size_t)255;
    return p;
  };
  int* counts = (int*)alloc((size_t)N * 4);
  int* rowst = (int*)alloc((size_t)N * 4);
  int* gbtot = (int*)alloc(512 * 4);
  int* gbase = (int*)alloc(512 * 4);
  int* gbcur = (int*)alloc(512 * 4);
  int* csr = (int*)alloc((size_t)E * 4);
  uint* regionX = (uint*)alloc((size_t)N * 64 * 4);  // 25.6 MB
  uint* h0buf = (uint*)alloc((size_t)N * 64 * 4);    // 25.6 MB
  uint4* wB0 = (uint4*)alloc(4096 * 16);
  uint4* wB1 = (uint4*)alloc(4096 * 16);
  uint4* wBm = (uint4*)alloc(1024 * 16);

  uint* xb = regionX;                      // N x 32 uints
  uint* agg0b = regionX + (size_t)N * 32;  // N x 32 uints
  uint* agg1 = regionX;                    // N x 64 uints (over dead xb/agg0b)
  int2* bed = (int2*)h0buf;                // E x 8 B = first N*32 uints
  uint* xm = h0buf + (size_t)N * 32;       // monotone u16 x (12.8 MB)

  hipMemsetAsync(gbtot, 0, 512 * 4, stream);

  int pairs = (N + 31) / 32;
  int lingrid = ceil_div(pairs, 4);        // ~1 MFMA tile per wave
  int mlpgrid = ceil_div((N + 15) / 16, 4);

  k_wprep<<<36, 256, 0, stream>>>(Wl0, Wr0, Wl1, Wr1, W1, wB0, wB1, wBm);
  k_prep<<<ceil_div(N * 32, 256), 256, 0, stream>>>(x, xb, xm, N * 32);
  k_bhist<<<ceil_div(E, ACHUNK), 256, 0, stream>>>(dst, gbtot, E);
  k_bscan<<<1, 512, 0, stream>>>(gbtot, gbase, gbcur);
  k_passA<<<ceil_div(E, ACHUNK), 256, 0, stream>>>(src, dst, gbcur, bed, E);
  k_passB<<<nb, 256, 0, stream>>>(bed, gbase, counts, rowst, csr, N, E);

  k_agg0b<<<2048, 256, 0, stream>>>(xm, rowst, counts, csr, agg0b, N);
  k_lin0<<<lingrid, 256, 0, stream>>>(agg0b, xb, wB0, bl0, g0, be0,
                                      (unsigned short*)h0buf, N);
  k_agg1s<<<2048, 256, 0, stream>>>((const uint4*)h0buf, rowst, counts, csr,
                                    (uint4*)agg1, N);
  k_lin1<<<lingrid, 256, 0, stream>>>(agg1, h0buf, wB1, bl1, g1, be1, N);
  k_mlp<<<mlpgrid, 256, 0, stream>>>(agg1, wBm, b1, W2, b2, out, N);
}

// Round 11
// 317.136 us; speedup vs baseline: 1.4841x; 1.4841x over previous
//
#include <hip/hip_runtime.h>
#include <math.h>

// ---------------------------------------------------------------------------
// GraphSAGE (max aggr) x2 + LN + ReLU + MLP head + sigmoid.
// Best-known config = round-7 structure (322.7 us) + packed bed + fused prep.
// - CSR build: 2-level LDS-staged counting sort; global bed packed to 4 B/edge
//   ((src<<8)|dst_off, bucket implicit in position; N < 2^17 nodes).
// - Gather-max in u16 pk_max domain, duplicate-padded 8-deep groups.
//   Layer-1 gather floor is structural: every XCD pulls ~all of h0 through
//   its L2 (8*25.6MB*(1-(7/8)^16)=180MB @ ~3.6TB/s fabric service ~= 58us).
//   Fusion (r8), wide gathers (r9), XCD slicing (r10) all failed to beat it.
// - MFMA GEMM layers read pre-packed bf16 B-fragments from global (L2-hot).
// Workspace ~58.9 MB, aliasing as in round 7.
// ---------------------------------------------------------------------------

static inline int ceil_div(int a, int b) { return (a + b - 1) / b; }

typedef unsigned int uint;
typedef __attribute__((ext_vector_type(8))) short short8;
typedef __attribute__((ext_vector_type(4))) float f32x4;

#define NBSHIFT 8     // bucket = 256 dst nodes
#define ACHUNK 4096   // edges per pass-A block
#define BCAP 6144     // LDS csr-window capacity per bucket

// RTNE float -> bf16
__device__ __forceinline__ unsigned short f2bf(float f) {
  uint u = __float_as_uint(f);
  u += 0x7fffu + ((u >> 16) & 1u);
  return (unsigned short)(u >> 16);
}
__device__ __forceinline__ float bfval(unsigned short b) {
  return __uint_as_float((uint)b << 16);
}
__device__ __forceinline__ uint pack2(float lo, float hi) {
  return (uint)f2bf(lo) | ((uint)f2bf(hi) << 16);
}
// packed unsigned 16-bit max (bf16>=0 compares correctly as u16)
__device__ __forceinline__ uint pkmaxu16(uint a, uint b) {
  uint r;
  asm("v_pk_max_u16 %0, %1, %2" : "=v"(r) : "v"(a), "v"(b));
  return r;
}

// ---- bucket scan ----------------------------------------------------------

__global__ __launch_bounds__(512) void k_bscan(const int* __restrict__ gbtot,
                                               int* __restrict__ gbase,
                                               int* __restrict__ gbcur) {
  __shared__ int tmp[512];
  int v = gbtot[threadIdx.x];
  tmp[threadIdx.x] = v;
  __syncthreads();
  for (int off = 1; off < 512; off <<= 1) {
    int t = (threadIdx.x >= off) ? tmp[threadIdx.x - off] : 0;
    __syncthreads();
    tmp[threadIdx.x] += t;
    __syncthreads();
  }
  int ex = tmp[threadIdx.x] - v;
  gbase[threadIdx.x] = ex;
  gbcur[threadIdx.x] = ex;
}

// ---- Fused prep: [0,prepB) x->xb/xm, [prepB,prepB+bhistB) bucket hist,
// [prepB+bhistB, ...) weight packing. All independent.

__global__ __launch_bounds__(256) void k_fprep(
    const float* __restrict__ x, uint* __restrict__ xb, uint* __restrict__ xm,
    int total, const int* __restrict__ dst, int* __restrict__ gbtot, int E,
    const float* __restrict__ Wl0, const float* __restrict__ Wr0,
    const float* __restrict__ Wl1, const float* __restrict__ Wr1,
    const float* __restrict__ W1m,
    uint4* __restrict__ wB0, uint4* __restrict__ wB1, uint4* __restrict__ wBm,
    int prepB, int bhistB) {
  __shared__ int bcnt[512];
  int bid = blockIdx.x, tid = threadIdx.x;
  if (bid < prepB) {
    int i = bid * 256 + tid;
    if (i < total) {
      float2 v = ((const float2*)x)[i];
      uint p = pack2(v.x, v.y);
      xb[i] = p;
      uint lo = p & 0xFFFFu, hi = p >> 16;
      lo = (lo & 0x8000u) ? (~lo & 0xFFFFu) : (lo | 0x8000u);
      hi = (hi & 0x8000u) ? (~hi & 0xFFFFu) : (hi | 0x8000u);
      xm[i] = lo | (hi << 16);
    }
  } else if (bid < prepB + bhistB) {
    int cb = bid - prepB;
    for (int i = tid; i < 512; i += 256) bcnt[i] = 0;
    __syncthreads();
    int c0 = cb * ACHUNK;
    int cend = min(c0 + ACHUNK, E);
    for (int e = c0 + tid; e < cend; e += 256)
      atomicAdd(&bcnt[dst[e] >> NBSHIFT], 1);
    __syncthreads();
    for (int i = tid; i < 512; i += 256) {
      int c = bcnt[i];
      if (c) atomicAdd(&gbtot[i], c);
    }
  } else {
    int i = (bid - prepB - bhistB) * 256 + tid;
    if (i < 4096) {
      int lane = i & 63, jt = (i >> 6) & 7, ks = i >> 9;
      int m = lane & 15, q = lane >> 4;
      int j = jt * 16 + m;
      int half = ks >> 2;             // 0 = hi, 1 = lo
      int kk = (ks & 3) * 32 + q * 8; // 0..120
      const float* srcr = (kk < 64) ? (Wl0 + (size_t)j * 64 + kk)
                                    : (Wr0 + (size_t)j * 64 + (kk - 64));
      float4 w0 = ((const float4*)srcr)[0];
      float4 w1 = ((const float4*)srcr)[1];
      float v[8] = {w0.x, w0.y, w0.z, w0.w, w1.x, w1.y, w1.z, w1.w};
      unsigned short b16[8];
#pragma unroll
      for (int t = 0; t < 8; t++) {
        unsigned short hi = f2bf(v[t]);
        b16[t] = half ? f2bf(v[t] - bfval(hi)) : hi;
      }
      uint4 p;
      p.x = (uint)b16[0] | ((uint)b16[1] << 16);
      p.y = (uint)b16[2] | ((uint)b16[3] << 16);
      p.z = (uint)b16[4] | ((uint)b16[5] << 16);
      p.w = (uint)b16[6] | ((uint)b16[7] << 16);
      wB0[i] = p;
    } else if (i < 8192) {
      int e = i - 4096;
      int lane = e & 63, jt = (e >> 6) & 7, ks = e >> 9;
      int m = lane & 15, q = lane >> 4;
      int j = jt * 16 + m;
      int k0 = ks * 32 + q * 8;  // 0..248
      const float* srcr = (k0 < 128) ? (Wl1 + (size_t)j * 128 + k0)
                                     : (Wr1 + (size_t)j * 128 + (k0 - 128));
      float4 w0 = ((const float4*)srcr)[0];
      float4 w1 = ((const float4*)srcr)[1];
      uint4 p;
      p.x = pack2(w0.x, w0.y);
      p.y = pack2(w0.z, w0.w);
      p.z = pack2(w1.x, w1.y);
      p.w = pack2(w1.z, w1.w);
      wB1[e] = p;
    } else if (i < 9216) {
      int e = i - 8192;
      int lane = e & 63, jt = (e >> 6) & 3, ks = e >> 8;
      int m = lane & 15, q = lane >> 4;
      int j = jt * 16 + m;          // 0..63
      int k0 = ks * 32 + q * 8;     // 0..120
      const float* srcr = W1m + (size_t)j * 128 + k0;
      float4 w0 = ((const float4*)srcr)[0];
      float4 w1 = ((const float4*)srcr)[1];
      uint4 p;
      p.x = pack2(w0.x, w0.y);
      p.y = pack2(w0.z, w0.w);
      p.z = pack2(w1.x, w1.y);
      p.w = pack2(w1.z, w1.w);
      wBm[e] = p;
    }
  }
}

// ---- Pass A: counting-sort edges into bucket-grouped packed bed[] ---------
// Global bed entry = (src<<8) | (dst & 255); bucket implicit in position.

__global__ __launch_bounds__(256) void k_passA(const int* __restrict__ src,
                                               const int* __restrict__ dst,
                                               int* __restrict__ gbcur,
                                               uint* __restrict__ bed, int E) {
  __shared__ int bcnt[512];
  __shared__ int lbase[512];
  __shared__ int bbase[512];
  __shared__ int lcur[512];
  __shared__ int2 sbed[ACHUNK];
  int tid = threadIdx.x;
  int c0 = blockIdx.x * ACHUNK;
  int cend = min(c0 + ACHUNK, E);
  int total = cend - c0;
  for (int i = tid; i < 512; i += 256) bcnt[i] = 0;
  __syncthreads();
  for (int e = c0 + tid; e < cend; e += 256)
    atomicAdd(&bcnt[dst[e] >> NBSHIFT], 1);
  __syncthreads();
  for (int i = tid; i < 512; i += 256) lbase[i] = bcnt[i];
  __syncthreads();
  for (int off = 1; off < 512; off <<= 1) {
    int i0 = tid, i1 = tid + 256;
    int v0 = (i0 >= off) ? lbase[i0 - off] : 0;
    int v1 = (i1 >= off) ? lbase[i1 - off] : 0;
    __syncthreads();
    lbase[i0] += v0;
    lbase[i1] += v1;
    __syncthreads();
  }
  for (int i = tid; i < 512; i += 256) {
    int c = bcnt[i];
    bbase[i] = (c > 0) ? atomicAdd(&gbcur[i], c) : 0;
    lcur[i] = 0;
  }
  __syncthreads();
  for (int e = c0 + tid; e < cend; e += 256) {
    int s = src[e], d = dst[e];
    int b = d >> NBSHIFT;
    int lp = atomicAdd(&lcur[b], 1);
    sbed[lbase[b] - bcnt[b] + lp] = make_int2(s, d);
  }
  __syncthreads();
  for (int j = tid; j < total; j += 256) {
    int2 pr = sbed[j];
    int b = pr.y >> NBSHIFT;
    bed[bbase[b] + (j - (lbase[b] - bcnt[b]))] =
        ((uint)pr.x << 8) | ((uint)pr.y & 255u);
  }
}

// ---- Pass B: one block per bucket; degrees/row-starts in LDS --------------

__global__ __launch_bounds__(256) void k_passB(const uint* __restrict__ bed,
                                               const int* __restrict__ gbase,
                                               int* __restrict__ counts,
                                               int* __restrict__ rowst,
                                               int* __restrict__ csr, int N, int E) {
  __shared__ int cnt[256];
  __shared__ int scn[256];
  __shared__ int lcur[256];
  __shared__ int scsr[BCAP];
  int b = blockIdx.x, tid = threadIdx.x;
  int n0 = b << NBSHIFT;
  int n1 = min(n0 + 256, N);
  int e0 = gbase[b];
  int e1 = (b + 1 < 512) ? gbase[b + 1] : E;
  if (b + 1 == gridDim.x) e1 = E;
  int sz = e1 - e0;
  cnt[tid] = 0;
  __syncthreads();
  for (int e = e0 + tid; e < e1; e += 256)
    atomicAdd(&cnt[bed[e] & 255u], 1);
  __syncthreads();
  scn[tid] = cnt[tid];
  __syncthreads();
  for (int off = 1; off < 256; off <<= 1) {
    int t = (tid >= off) ? scn[tid - off] : 0;
    __syncthreads();
    scn[tid] += t;
    __syncthreads();
  }
  int ex = scn[tid] - cnt[tid];
  if (n0 + tid < n1) {
    counts[n0 + tid] = cnt[tid];
    rowst[n0 + tid] = e0 + ex;
  }
  lcur[tid] = ex;
  __syncthreads();
  if (sz <= BCAP) {
    for (int e = e0 + tid; e < e1; e += 256) {
      uint pr = bed[e];
      int p = atomicAdd(&lcur[pr & 255u], 1);
      scsr[p] = (int)(pr >> 8);
    }
    __syncthreads();
    for (int j = tid; j < sz; j += 256) csr[e0 + j] = scsr[j];
  } else {  // statistical overflow fallback (correct, slower)
    for (int e = e0 + tid; e < e1; e += 256) {
      uint pr = bed[e];
      int p = atomicAdd(&lcur[pr & 255u], 1);
      csr[e0 + p] = (int)(pr >> 8);
    }
  }
}

// ---- Aggregation layer 0: monotone-u16 pk_max, 2 nodes/wave, dup-padded ---

__global__ __launch_bounds__(256) void k_agg0b(const uint* __restrict__ xm,
                                               const int* __restrict__ rowst,
                                               const int* __restrict__ deg,
                                               const int* __restrict__ csr,
                                               uint* __restrict__ agg, int N) {
  int lane = threadIdx.x & 63;
  int sub = lane >> 5, ll = lane & 31;
  int h = sub << 5;
  int w = (blockIdx.x * 256 + threadIdx.x) >> 6;
  int nw = (gridDim.x * 256) >> 6;
  for (int n0 = w * 2; n0 < N; n0 += nw * 2) {
    int n = n0 + sub;
    bool valid = (n < N);
    int myn = valid ? n : (N - 1);
    int rs = rowst[myn], d = deg[myn];
    int dmax = max(d, __shfl_xor(d, 32));
    int fb = (d > 0) ? csr[rs] : 0;
    uint m = 0;
    for (int base = 0; base < dmax; base += 32) {
      int cnt = min(max(d - base, 0), 32);
      int cmax = min(dmax - base, 32);
      int idx = (ll < cnt) ? csr[rs + base + ll] : fb;
      for (int j = 0; j < cmax; j += 8) {
        uint u0 = xm[(size_t)__shfl(idx, h + j + 0) * 32 + ll];
        uint u1 = xm[(size_t)__shfl(idx, h + j + 1) * 32 + ll];
        uint u2 = xm[(size_t)__shfl(idx, h + j + 2) * 32 + ll];
        uint u3 = xm[(size_t)__shfl(idx, h + j + 3) * 32 + ll];
        uint u4 = xm[(size_t)__shfl(idx, h + j + 4) * 32 + ll];
        uint u5 = xm[(size_t)__shfl(idx, h + j + 5) * 32 + ll];
        uint u6 = xm[(size_t)__shfl(idx, h + j + 6) * 32 + ll];
        uint u7 = xm[(size_t)__shfl(idx, h + j + 7) * 32 + ll];
        m = pkmaxu16(m, pkmaxu16(pkmaxu16(pkmaxu16(u0, u1), pkmaxu16(u2, u3)),
                                 pkmaxu16(pkmaxu16(u4, u5), pkmaxu16(u6, u7))));
      }
    }
    if (valid) {
      uint lo = m & 0xFFFFu, hi = m >> 16;
      lo = (lo & 0x8000u) ? (lo ^ 0x8000u) : (~lo & 0xFFFFu);
      hi = (hi & 0x8000u) ? (hi ^ 0x8000u) : (~hi & 0xFFFFu);
      agg[(size_t)n * 32 + ll] = (d > 0) ? (lo | (hi << 16)) : 0u;
    }
  }
}

// ---- Aggregation layer 1: h0 >= 0 -> plain v_pk_max_u16, dup-padded -------

__global__ __launch_bounds__(256) void k_agg1(const uint* __restrict__ h0,
                                              const int* __restrict__ rowst,
                                              const int* __restrict__ deg,
                                              const int* __restrict__ csr,
                                              uint* __restrict__ agg, int N) {
  int lane = threadIdx.x & 63;
  int wid = (blockIdx.x * 256 + threadIdx.x) >> 6;
  int nw = (gridDim.x * 256) >> 6;
  for (int n = wid; n < N; n += nw) {
    int rs = rowst[n], d = deg[n];
    uint m = 0;
    if (d > 0) {
      int fb = csr[rs];
      for (int base = 0; base < d; base += 64) {
        int cnt = min(d - base, 64);
        int idx = (lane < cnt) ? csr[rs + base + lane] : fb;
        for (int j = 0; j < cnt; j += 8) {
          uint u0 = h0[(size_t)__shfl(idx, j + 0) * 64 + lane];
          uint u1 = h0[(size_t)__shfl(idx, j + 1) * 64 + lane];
          uint u2 = h0[(size_t)__shfl(idx, j + 2) * 64 + lane];
          uint u3 = h0[(size_t)__shfl(idx, j + 3) * 64 + lane];
          uint u4 = h0[(size_t)__shfl(idx, j + 4) * 64 + lane];
          uint u5 = h0[(size_t)__shfl(idx, j + 5) * 64 + lane];
          uint u6 = h0[(size_t)__shfl(idx, j + 6) * 64 + lane];
          uint u7 = h0[(size_t)__shfl(idx, j + 7) * 64 + lane];
          m = pkmaxu16(m, pkmaxu16(pkmaxu16(pkmaxu16(u0, u1), pkmaxu16(u2, u3)),
                                   pkmaxu16(pkmaxu16(u4, u5), pkmaxu16(u6, u7))));
        }
      }
    }
    agg[(size_t)n * 64 + lane] = m;  // m==0 for empty == required semantics
  }
}

// ---- Layer 0: h0 = LNrelu([agg0|x] @ [Wl0|Wr0]^T + bl0) -------------------

__global__ __launch_bounds__(256) void k_lin0(
    const uint* __restrict__ agg,  // N x 32 uints (bf16 [N][64])
    const uint* __restrict__ xb,   // N x 32 uints
    const uint4* __restrict__ wB,  // 4096 frag entries
    const float* __restrict__ bl, const float* __restrict__ g,
    const float* __restrict__ be, unsigned short* __restrict__ hout, int N) {
  int lane = threadIdx.x & 63, m = lane & 15, q = lane >> 4;
  int w = (blockIdx.x * 256 + threadIdx.x) >> 6;
  int nw = (gridDim.x * 256) >> 6;
  int pairs = (N + 31) / 32;
  float blv[8], gv[8], bev[8];
#pragma unroll
  for (int jt = 0; jt < 8; jt++) {
    blv[jt] = bl[jt * 16 + m];
    gv[jt] = g[jt * 16 + m];
    bev[jt] = be[jt * 16 + m];
  }
  for (int p = w; p < pairs; p += nw) {
    int b0 = p * 32;
    short8 a[2][4];
#pragma unroll
    for (int t = 0; t < 2; t++) {
      int row = b0 + t * 16 + m;
      const uint* r0 = agg + (size_t)row * 32;
      const uint* r1 = xb + (size_t)row * 32;
#pragma unroll
      for (int ks = 0; ks < 4; ks++) {
        const uint* base = (ks < 2) ? r0 : r1;
        a[t][ks] = __builtin_bit_cast(short8, *(const uint4*)(base + (ks & 1) * 16 + q * 4));
      }
    }
    f32x4 acc[2][8];
#pragma unroll
    for (int t = 0; t < 2; t++)
#pragma unroll
      for (int jt = 0; jt < 8; jt++) acc[t][jt] = {0.f, 0.f, 0.f, 0.f};
#pragma unroll
    for (int ks = 0; ks < 8; ks++) {
#pragma unroll
      for (int jt = 0; jt < 8; jt++) {
        short8 b = __builtin_bit_cast(short8, wB[(ks * 8 + jt) * 64 + lane]);
        acc[0][jt] = __builtin_amdgcn_mfma_f32_16x16x32_bf16(a[0][ks & 3], b, acc[0][jt], 0, 0, 0);
        acc[1][jt] = __builtin_amdgcn_mfma_f32_16x16x32_bf16(a[1][ks & 3], b, acc[1][jt], 0, 0, 0);
      }
    }
#pragma unroll
    for (int t = 0; t < 2; t++) {
      float s1[4] = {0.f, 0.f, 0.f, 0.f}, s2[4] = {0.f, 0.f, 0.f, 0.f};
#pragma unroll
      for (int jt = 0; jt < 8; jt++) {
        float bb = blv[jt];
#pragma unroll
        for (int r = 0; r < 4; r++) {
          float v = acc[t][jt][r] + bb;
          s1[r] += v;
          s2[r] += v * v;
        }
      }
#pragma unroll
      for (int off = 1; off < 16; off <<= 1) {
#pragma unroll
        for (int r = 0; r < 4; r++) {
          s1[r] += __shfl_xor(s1[r], off);
          s2[r] += __shfl_xor(s2[r], off);
        }
      }
      float mu[4], rstd[4];
#pragma unroll
      for (int r = 0; r < 4; r++) {
        mu[r] = s1[r] * (1.0f / 128.0f);
        float var = s2[r] * (1.0f / 128.0f) - mu[r] * mu[r];
        rstd[r] = rsqrtf(var + 1e-5f);
      }
      int nodeb = b0 + t * 16 + q * 4;
#pragma unroll
      for (int jt = 0; jt < 8; jt++) {
        float bb = blv[jt];
#pragma unroll
        for (int r = 0; r < 4; r++) {
          int node = nodeb + r;
          if (node < N) {
            float v = acc[t][jt][r] + bb;
            float o = fmaxf((v - mu[r]) * rstd[r] * gv[jt] + bev[jt], 0.0f);
            hout[(size_t)node * 128 + jt * 16 + m] = f2bf(o);
          }
        }
      }
    }
  }
}

// ---- Layer 1: h1 = LNrelu([agg1|h0] @ [Wl1|Wr1]^T + bl1), in-place --------

__global__ __launch_bounds__(256) void k_lin1(
    uint* agg,                     // N x 64 uints; becomes h1 (bf16 [N][128])
    const uint* __restrict__ h0,   // N x 64 uints
    const uint4* __restrict__ wB,  // 4096 frag entries
    const float* __restrict__ bl, const float* __restrict__ g,
    const float* __restrict__ be, int N) {
  int lane = threadIdx.x & 63, m = lane & 15, q = lane >> 4;
  int w = (blockIdx.x * 256 + threadIdx.x) >> 6;
  int nw = (gridDim.x * 256) >> 6;
  int pairs = (N + 31) / 32;
  float blv[8], gv[8], bev[8];
#pragma unroll
  for (int jt = 0; jt < 8; jt++) {
    blv[jt] = bl[jt * 16 + m];
    gv[jt] = g[jt * 16 + m];
    bev[jt] = be[jt * 16 + m];
  }
  unsigned short* hout = (unsigned short*)agg;
  for (int p = w; p < pairs; p += nw) {
    int b0 = p * 32;
    short8 a[2][8];
#pragma unroll
    for (int t = 0; t < 2; t++) {
      int row = b0 + t * 16 + m;
      const uint* r0 = agg + (size_t)row * 64;
      const uint* r1 = h0 + (size_t)row * 64;
#pragma unroll
      for (int ks = 0; ks < 8; ks++) {
        const uint* base = (ks < 4) ? r0 : r1;
        a[t][ks] = __builtin_bit_cast(short8, *(const uint4*)(base + (ks & 3) * 16 + q * 4));
      }
    }
    f32x4 acc[2][8];
#pragma unroll
    for (int t = 0; t < 2; t++)
#pragma unroll
      for (int jt = 0; jt < 8; jt++) acc[t][jt] = {0.f, 0.f, 0.f, 0.f};
#pragma unroll
    for (int ks = 0; ks < 8; ks++) {
#pragma unroll
      for (int jt = 0; jt < 8; jt++) {
        short8 b = __builtin_bit_cast(short8, wB[(ks * 8 + jt) * 64 + lane]);
        acc[0][jt] = __builtin_amdgcn_mfma_f32_16x16x32_bf16(a[0][ks], b, acc[0][jt], 0, 0, 0);
        acc[1][jt] = __builtin_amdgcn_mfma_f32_16x16x32_bf16(a[1][ks], b, acc[1][jt], 0, 0, 0);
      }
    }
#pragma unroll
    for (int t = 0; t < 2; t++) {
      float s1[4] = {0.f, 0.f, 0.f, 0.f}, s2[4] = {0.f, 0.f, 0.f, 0.f};
#pragma unroll
      for (int jt = 0; jt < 8; jt++) {
        float bb = blv[jt];
#pragma unroll
        for (int r = 0; r < 4; r++) {
          float v = acc[t][jt][r] + bb;
          s1[r] += v;
          s2[r] += v * v;
        }
      }
#pragma unroll
      for (int off = 1; off < 16; off <<= 1) {
#pragma unroll
        for (int r = 0; r < 4; r++) {
          s1[r] += __shfl_xor(s1[r], off);
          s2[r] += __shfl_xor(s2[r], off);
        }
      }
      float mu[4], rstd[4];
#pragma unroll
      for (int r = 0; r < 4; r++) {
        mu[r] = s1[r] * (1.0f / 128.0f);
        float var = s2[r] * (1.0f / 128.0f) - mu[r] * mu[r];
        rstd[r] = rsqrtf(var + 1e-5f);
      }
      int nodeb = b0 + t * 16 + q * 4;
#pragma unroll
      for (int jt = 0; jt < 8; jt++) {
        float bb = blv[jt];
#pragma unroll
        for (int r = 0; r < 4; r++) {
          int node = nodeb + r;
          if (node < N) {
            float v = acc[t][jt][r] + bb;
            float o = fmaxf((v - mu[r]) * rstd[r] * gv[jt] + bev[jt], 0.0f);
            hout[(size_t)node * 128 + jt * 16 + m] = f2bf(o);
          }
        }
      }
    }
  }
}

// ---- MLP head: out = sigmoid(relu(h1@W1.T+b1) @ W2.T + b2) ----------------

__global__ __launch_bounds__(256) void k_mlp(const uint* __restrict__ h1,
                                             const uint4* __restrict__ wB,
                                             const float* __restrict__ b1,
                                             const float* __restrict__ W2,
                                             const float* __restrict__ b2,
                                             float* __restrict__ out, int N) {
  int lane = threadIdx.x & 63, m = lane & 15, q = lane >> 4;
  int w = (blockIdx.x * 256 + threadIdx.x) >> 6;
  int nw = (gridDim.x * 256) >> 6;
  int tiles = (N + 15) / 16;
  float b1v[4], w2v[4];
#pragma unroll
  for (int jt = 0; jt < 4; jt++) {
    b1v[jt] = b1[jt * 16 + m];
    w2v[jt] = W2[jt * 16 + m];
  }
  float b2v = b2[0];
  for (int tl = w; tl < tiles; tl += nw) {
    int b0 = tl * 16;
    int row = min(b0 + m, N - 1);
    const uint* r0 = h1 + (size_t)row * 64;
    short8 a[4];
#pragma unroll
    for (int ks = 0; ks < 4; ks++)
      a[ks] = __builtin_bit_cast(short8, *(const uint4*)(r0 + ks * 16 + q * 4));
    f32x4 acc[4];
#pragma unroll
    for (int jt = 0; jt < 4; jt++) acc[jt] = {0.f, 0.f, 0.f, 0.f};
#pragma unroll
    for (int ks = 0; ks < 4; ks++) {
#pragma unroll
      for (int jt = 0; jt < 4; jt++) {
        short8 b = __builtin_bit_cast(short8, wB[(ks * 4 + jt) * 64 + lane]);
        acc[jt] = __builtin_amdgcn_mfma_f32_16x16x32_bf16(a[ks], b, acc[jt], 0, 0, 0);
      }
    }
    float part[4] = {0.f, 0.f, 0.f, 0.f};
#pragma unroll
    for (int jt = 0; jt < 4; jt++) {
#pragma unroll
      for (int r = 0; r < 4; r++)
        part[r] += fmaxf(acc[jt][r] + b1v[jt], 0.0f) * w2v[jt];
    }
#pragma unroll
    for (int off = 1; off < 16; off <<= 1) {
#pragma unroll
      for (int r = 0; r < 4; r++) part[r] += __shfl_xor(part[r], off);
    }
    if (m == 0) {
#pragma unroll
      for (int r = 0; r < 4; r++) {
        int node = b0 + q * 4 + r;
        if (node < N) out[node] = 1.0f / (1.0f + expf(-(part[r] + b2v)));
      }
    }
  }
}

// ---------------------------------------------------------------------------

extern "C" void kernel_launch(void* const* d_in, const int* in_sizes, int n_in,
                              void* d_out, int out_size, void* d_ws, size_t ws_size,
                              hipStream_t stream) {
  const float* x = (const float*)d_in[0];
  const int* ei = (const int*)d_in[1];
  const float* Wl0 = (const float*)d_in[2];
  const float* bl0 = (const float*)d_in[3];
  const float* Wr0 = (const float*)d_in[4];
  const float* g0 = (const float*)d_in[5];
  const float* be0 = (const float*)d_in[6];
  const float* Wl1 = (const float*)d_in[7];
  const float* bl1 = (const float*)d_in[8];
  const float* Wr1 = (const float*)d_in[9];
  const float* g1 = (const float*)d_in[10];
  const float* be1 = (const float*)d_in[11];
  const float* W1 = (const float*)d_in[12];
  const float* b1 = (const float*)d_in[13];
  const float* W2 = (const float*)d_in[14];
  const float* b2 = (const float*)d_in[15];
  float* out = (float*)d_out;

  const int N = in_sizes[0] / 64;
  const int E = in_sizes[1] / 2;
  const int* src = ei;
  const int* dst = ei + E;
  const int nb = ceil_div(N, 1 << NBSHIFT);

  // Workspace (~58.9 MB peak):
  //   misc + csr (6.4 MB) + regionX (25.6 MB) + h0buf (25.6 MB) + wB (144 KB)
  // h0buf timeline: [bed 6.4 | xm 12.8] -> h0 (k_lin0 onward).
  // regionX timeline: [xb | agg0b] -> agg1 -> h1 (in-place).
  char* ws = (char*)d_ws;
  size_t off = 0;
  auto alloc = [&](size_t bytes) -> void* {
    void* p = ws + off;
    off = (off + bytes + 255) & ~(size_t)255;
    return p;
  };
  int* counts = (int*)alloc((size_t)N * 4);
  int* rowst = (int*)alloc((size_t)N * 4);
  int* gbtot = (int*)alloc(512 * 4);
  int* gbase = (int*)alloc(512 * 4);
  int* gbcur = (int*)alloc(512 * 4);
  int* csr = (int*)alloc((size_t)E * 4);
  uint* regionX = (uint*)alloc((size_t)N * 64 * 4);  // 25.6 MB
  uint* h0buf = (uint*)alloc((size_t)N * 64 * 4);    // 25.6 MB
  uint4* wB0 = (uint4*)alloc(4096 * 16);
  uint4* wB1 = (uint4*)alloc(4096 * 16);
  uint4* wBm = (uint4*)alloc(1024 * 16);

  uint* xb = regionX;                      // N x 32 uints
  uint* agg0b = regionX + (size_t)N * 32;  // N x 32 uints
  uint* agg1 = regionX;                    // N x 64 uints (over dead xb/agg0b)
  uint* bed = h0buf;                       // E x 4 B packed (src<<8|dst&255)
  uint* xm = h0buf + (size_t)N * 32;       // monotone u16 x (12.8 MB)

  hipMemsetAsync(gbtot, 0, 512 * 4, stream);

  int pairs = (N + 31) / 32;
  int lingrid = ceil_div(pairs, 4);        // ~1 MFMA tile per wave
  int mlpgrid = ceil_div((N + 15) / 16, 4);

  int prepB = ceil_div(N * 32, 256);
  int bhistB = ceil_div(E, ACHUNK);
  int wprepB = 36;
  k_fprep<<<prepB + bhistB + wprepB, 256, 0, stream>>>(
      x, xb, xm, N * 32, dst, gbtot, E, Wl0, Wr0, Wl1, Wr1, W1,
      wB0, wB1, wBm, prepB, bhistB);
  k_bscan<<<1, 512, 0, stream>>>(gbtot, gbase, gbcur);
  k_passA<<<ceil_div(E, ACHUNK), 256, 0, stream>>>(src, dst, gbcur, bed, E);
  k_passB<<<nb, 256, 0, stream>>>(bed, gbase, counts, rowst, csr, N, E);

  k_agg0b<<<2048, 256, 0, stream>>>(xm, rowst, counts, csr, agg0b, N);
  k_lin0<<<lingrid, 256, 0, stream>>>(agg0b, xb, wB0, bl0, g0, be0,
                                      (unsigned short*)h0buf, N);
  k_agg1<<<2048, 256, 0, stream>>>(h0buf, rowst, counts, csr, agg1, N);
  k_lin1<<<lingrid, 256, 0, stream>>>(agg1, h0buf, wB1, bl1, g1, be1, N);
  k_mlp<<<mlpgrid, 256, 0, stream>>>(agg1, wBm, b1, W2, b2, out, N);
}